// Round 11
// baseline (401.939 us; speedup 1.0000x reference)
//
#include <hip/hip_runtime.h>
#include <hip/hip_bf16.h>
#include <stdint.h>

// ---------- types ----------
using bf16x8 = __attribute__((ext_vector_type(8))) __bf16;
using s16x8  = __attribute__((ext_vector_type(8))) short;
using f32x4  = __attribute__((ext_vector_type(4))) float;

__device__ __forceinline__ uint16_t f2bf(float f) {
    uint32_t u = __builtin_bit_cast(uint32_t, f);
    u += 0x7fffu + ((u >> 16) & 1u);   // RNE
    return (uint16_t)(u >> 16);
}
__device__ __forceinline__ float bf2f(uint16_t h) {
    return __builtin_bit_cast(float, (uint32_t)h << 16);
}

__device__ __forceinline__ void async16(uint16_t* lds_dst, const uint16_t* g_src) {
    __builtin_amdgcn_global_load_lds(
        (const __attribute__((address_space(1))) void*)g_src,
        (__attribute__((address_space(3))) void*)lds_dst,
        16, 0, 0);
}

// ---------- xtw: x f32 -> xb + xT, plus merged weight prep (blocks >= 16384) ----------
__global__ __launch_bounds__(256, 4)
void xtw_k(const float* __restrict__ x, const float* __restrict__ wqkv,
           const float* __restrict__ wout,
           uint16_t* __restrict__ xb, uint16_t* __restrict__ xT,
           uint16_t* __restrict__ wqTs, uint16_t* __restrict__ wkT,
           uint16_t* __restrict__ woutT, uint16_t* __restrict__ wv_rm)
{
    __shared__ uint16_t lt[64 * 68];
    const int tid = threadIdx.x;
    const int bi = blockIdx.x;
    if (bi >= 16384) {
        int sec = (bi - 16384) >> 10;
        int idx = ((bi - 16384) & 1023) * 256 + tid;   // over 512*512
        int co = idx >> 9, r = idx & 511;
        if (sec == 0) {
            wqTs[co * 512 + r] = f2bf(wqkv[r * 1536 + co] * 0.125f);
        } else if (sec == 1) {
            wkT[co * 512 + r] = f2bf(wqkv[r * 1536 + 512 + co]);
        } else if (sec == 2) {
            woutT[co * 512 + r] = f2bf(wout[r * 512 + co]);
        } else {
            wv_rm[co * 512 + r] = f2bf(wqkv[co * 1536 + 1024 + r]);
        }
        return;
    }
    const int b = bi >> 9;
    const int rem = bi & 511;
    const int st = rem >> 3, ct = rem & 7;     // 64-spatial x 64-chan tile
    const int c4 = (tid & 15) * 4;
#pragma unroll
    for (int rep = 0; rep < 4; ++rep) {
        int r = (tid >> 4) + rep * 16;
        long gs = (long)(b * 4096 + st * 64 + r) * 512 + ct * 64 + c4;
        float4 v = *(const float4*)(x + gs);
        uint16_t t[4];
        t[0] = f2bf(v.x); t[1] = f2bf(v.y); t[2] = f2bf(v.z); t[3] = f2bf(v.w);
        *(ushort4*)(xb + gs) = *(const ushort4*)t;
#pragma unroll
        for (int q = 0; q < 4; ++q) lt[r * 68 + c4 + q] = t[q];
    }
    __syncthreads();
    const int s4 = (tid & 15) * 4;
#pragma unroll
    for (int rep = 0; rep < 4; ++rep) {
        int c = (tid >> 4) + rep * 16;
        uint16_t t[4];
#pragma unroll
        for (int q = 0; q < 4; ++q) t[q] = lt[(s4 + q) * 68 + c];
        *(ushort4*)(xT + (long)(b * 512 + ct * 64 + c) * 4096 + st * 64 + s4) =
            *(const ushort4*)t;
    }
}

// ---------- g128G: Gram, unsplit K=4096, 128x128 tiles (32 KiB, 4-resident) ----------
// Per b: 4x4 tile grid, keep j>=i (10 tiles) + mirror epilogue. grid = 32*10 = 320.
__global__ __launch_bounds__(256, 4)
void g128G_k(const uint16_t* __restrict__ X, uint16_t* __restrict__ G)
{
    __shared__ uint16_t Al[8192];
    __shared__ uint16_t Bl[8192];
    const int tid  = threadIdx.x;
    const int lane = tid & 63;
    const int wv   = tid >> 6;
    const int wr   = wv >> 1, wc = wv & 1;

    const int q8 = gridDim.x >> 3;   // 40
    const int l  = (blockIdx.x & 7) * q8 + (blockIdx.x >> 3);
    const int b  = l / 10;
    const int t  = l - b * 10;
    const int i  = (t < 4) ? 0 : ((t < 7) ? 1 : ((t < 9) ? 2 : 3));
    const int j  = t - ((i == 0) ? 0 : (i == 1) ? 3 : (i == 2) ? 5 : 6);

    const uint16_t* xbase = X + (long)b * 512 * 4096;
    const uint16_t* arow  = xbase + (long)i * 128 * 4096;
    const uint16_t* brow  = xbase + (long)j * 128 * 4096;

    f32x4 acc[4][4];
#pragma unroll
    for (int m = 0; m < 4; ++m)
#pragma unroll
        for (int n = 0; n < 4; ++n) acc[m][n] = (f32x4){0.f, 0.f, 0.f, 0.f};

    for (int k0 = 0; k0 < 4096; k0 += 64) {
#pragma unroll
        for (int s2 = 0; s2 < 4; ++s2) {
            int cb  = s2 * 256 + wv * 64;
            int ci  = cb + lane;
            int row = ci >> 3;
            int cs  = (ci & 7) ^ (row & 7);
            async16(&Al[cb * 8], arow + (long)row * 4096 + k0 + cs * 8);
            async16(&Bl[cb * 8], brow + (long)row * 4096 + k0 + cs * 8);
        }
        __syncthreads();
#pragma unroll
        for (int ks = 0; ks < 2; ++ks) {
            bf16x8 af[4], bfr[4];
#pragma unroll
            for (int m = 0; m < 4; ++m) {
                int row = wr * 64 + m * 16 + (lane & 15);
                int ch  = ks * 4 + (lane >> 4);
                af[m] = __builtin_bit_cast(bf16x8,
                    *(const s16x8*)&Al[row * 64 + ((ch ^ (row & 7)) * 8)]);
            }
#pragma unroll
            for (int n = 0; n < 4; ++n) {
                int row = wc * 64 + n * 16 + (lane & 15);
                int ch  = ks * 4 + (lane >> 4);
                bfr[n] = __builtin_bit_cast(bf16x8,
                    *(const s16x8*)&Bl[row * 64 + ((ch ^ (row & 7)) * 8)]);
            }
#pragma unroll
            for (int m = 0; m < 4; ++m)
#pragma unroll
                for (int n = 0; n < 4; ++n)
                    acc[m][n] = __builtin_amdgcn_mfma_f32_16x16x32_bf16(
                        af[m], bfr[n], acc[m][n], 0, 0, 0);
        }
        __syncthreads();
    }

    uint16_t* o = G + (long)b * 262144;
    const int row0 = i * 128 + wr * 64;
    const int col0 = j * 128 + wc * 64;
#pragma unroll
    for (int m = 0; m < 4; ++m) {
#pragma unroll
        for (int r = 0; r < 4; ++r) {
            int row = row0 + m * 16 + (lane >> 4) * 4 + r;
#pragma unroll
            for (int n = 0; n < 4; ++n)
                o[(long)row * 512 + col0 + n * 16 + (lane & 15)] = f2bf(acc[m][n][r]);
        }
        if (i != j) {
            int rbase = row0 + m * 16 + (lane >> 4) * 4;
#pragma unroll
            for (int n = 0; n < 4; ++n) {
                int col = col0 + n * 16 + (lane & 15);
                uint16_t tt[4];
#pragma unroll
                for (int r = 0; r < 4; ++r) tt[r] = f2bf(acc[m][n][r]);
                *(ushort4*)&o[(long)col * 512 + rbase] = *(const ushort4*)tt;
            }
        }
    }
}

// ---------- simfull: T1t = WkT·G (K=512, BK=32, 3-buf pipelined) -> sim -> softmax ----------
__global__ __launch_bounds__(512, 1)
void simfull_k(const uint16_t* __restrict__ G, const uint16_t* __restrict__ wkT,
               const uint16_t* __restrict__ wqTs, uint16_t* __restrict__ attn)
{
    __shared__ uint16_t sm[73728];   // 147,456 B
    const int tid  = threadIdx.x;
    const int lane = tid & 63;
    const int wv   = tid >> 6;
    const int fr   = lane & 15;
    const int hi4  = lane >> 4;
    const int bi = blockIdx.x;
    const int h = bi >> 5;
    const int b = (bi & 7) * 4 + ((bi >> 3) & 3);   // same-b blocks share an XCD

    const uint16_t* gb  = G + (long)b * 262144;         // [512][512] bf16
    const uint16_t* ab  = wkT + (long)h * 64 * 512;
    const uint16_t* qb2 = wqTs + (long)h * 64 * 512;

    auto stg = [&](int q, int t) {
        const int k0 = t * 32;
#pragma unroll
        for (int i = 0; i < 4; ++i) {
            int si = i * 64 + lane;
            int rr = si >> 2, cc = (si & 3) ^ ((rr >> 1) & 3);
            async16(&sm[q * 16384 + wv * 2048 + i * 512],
                    gb + (long)(wv * 64 + rr) * 512 + k0 + cc * 8);
        }
        {
            int si = (wv & 3) * 64 + lane;
            int rr = si >> 2, cc = (si & 3) ^ ((rr >> 1) & 3);
            async16(&sm[49152 + q * 4096 + (wv >> 2) * 2048 + (wv & 3) * 512],
                    ab + (long)rr * 512 + k0 + cc * 8);
        }
    };

    f32x4 acc[4][4];
#pragma unroll
    for (int mf = 0; mf < 4; ++mf)
#pragma unroll
        for (int nf = 0; nf < 4; ++nf) acc[mf][nf] = (f32x4){0.f, 0.f, 0.f, 0.f};

    const int sa = (hi4 ^ ((fr >> 1) & 3)) * 8;

    stg(0, 0);
    stg(1, 1);
    asm volatile("s_waitcnt vmcnt(5)" ::: "memory");
    __builtin_amdgcn_sched_barrier(0);
    __builtin_amdgcn_s_barrier();

    for (int t = 0; t < 16; ++t) {
        const int q = t % 3;
        if (t + 2 < 16) stg((t + 2) % 3, t + 2);
        bf16x8 af[4], bfq[4];
        const int wkb = 49152 + q * 4096 + (wv >> 2) * 2048;
#pragma unroll
        for (int mf = 0; mf < 4; ++mf)
            af[mf] = __builtin_bit_cast(bf16x8,
                *(const s16x8*)&sm[wkb + (mf * 16 + fr) * 32 + sa]);
#pragma unroll
        for (int nf = 0; nf < 4; ++nf)
            bfq[nf] = __builtin_bit_cast(bf16x8,
                *(const s16x8*)&sm[q * 16384 + wv * 2048 + (nf * 16 + fr) * 32 + sa]);
        asm volatile("s_waitcnt lgkmcnt(0)" ::: "memory");
        __builtin_amdgcn_sched_barrier(0);
        __builtin_amdgcn_s_setprio(1);
#pragma unroll
        for (int mf = 0; mf < 4; ++mf)
#pragma unroll
            for (int nf = 0; nf < 4; ++nf)
                acc[mf][nf] = __builtin_amdgcn_mfma_f32_16x16x32_bf16(
                    af[mf], bfq[nf], acc[mf][nf], 0, 0, 0);
        __builtin_amdgcn_s_setprio(0);
        if (t + 2 < 16) { asm volatile("s_waitcnt vmcnt(5)" ::: "memory"); }
        else            { asm volatile("s_waitcnt vmcnt(0)" ::: "memory"); }
        __builtin_amdgcn_sched_barrier(0);
        __builtin_amdgcn_s_barrier();
    }

    // ---- write T1t hi/lo bf16 [64 j][512 c], chunk-XOR swizzled ----
#pragma unroll
    for (int mf = 0; mf < 4; ++mf)
#pragma unroll
        for (int nf = 0; nf < 4; ++nf)
#pragma unroll
            for (int r = 0; r < 4; ++r) {
                int jj2 = mf * 16 + hi4 * 4 + r;
                int c = wv * 64 + nf * 16 + fr;
                float v = acc[mf][nf][r];
                uint16_t hi = f2bf(v);
                int off = jj2 * 512 + ((c >> 3) ^ (jj2 & 7)) * 8 + (c & 7);
                sm[off] = hi;
                sm[32768 + off] = f2bf(v - bf2f(hi));
            }
    __syncthreads();

    // ---- stage2: sim partial over c-slice [wv*64, wv*64+64), hi + lo ----
    f32x4 a2[4][4];
#pragma unroll
    for (int mf = 0; mf < 4; ++mf)
#pragma unroll
        for (int nf = 0; nf < 4; ++nf) a2[mf][nf] = (f32x4){0.f, 0.f, 0.f, 0.f};
#pragma unroll
    for (int ks = 0; ks < 2; ++ks) {
        bf16x8 af[4], bh[4], bl[4];
#pragma unroll
        for (int mf = 0; mf < 4; ++mf)
            af[mf] = __builtin_bit_cast(bf16x8,
                *(const s16x8*)&qb2[(long)(mf * 16 + fr) * 512 + wv * 64 + ks * 32 + hi4 * 8]);
#pragma unroll
        for (int nf = 0; nf < 4; ++nf) {
            int jj2 = nf * 16 + fr;
            int ch = (wv * 8 + ks * 4 + hi4) ^ (fr & 7);
            bh[nf] = __builtin_bit_cast(bf16x8, *(const s16x8*)&sm[jj2 * 512 + ch * 8]);
            bl[nf] = __builtin_bit_cast(bf16x8, *(const s16x8*)&sm[32768 + jj2 * 512 + ch * 8]);
        }
#pragma unroll
        for (int mf = 0; mf < 4; ++mf)
#pragma unroll
            for (int nf = 0; nf < 4; ++nf) {
                a2[mf][nf] = __builtin_amdgcn_mfma_f32_16x16x32_bf16(
                    af[mf], bh[nf], a2[mf][nf], 0, 0, 0);
                a2[mf][nf] = __builtin_amdgcn_mfma_f32_16x16x32_bf16(
                    af[mf], bl[nf], a2[mf][nf], 0, 0, 0);
            }
    }

    float* red = (float*)&sm[65536];
    for (int w = 0; w < 8; ++w) {
        if (wv == w) {
#pragma unroll
            for (int mf = 0; mf < 4; ++mf)
#pragma unroll
                for (int nf = 0; nf < 4; ++nf)
#pragma unroll
                    for (int r = 0; r < 4; ++r) {
                        int ii = mf * 16 + hi4 * 4 + r;
                        int jj2 = nf * 16 + fr;
                        float* p = &red[ii * 64 + jj2];
                        *p = (w == 0) ? a2[mf][nf][r] : (*p + a2[mf][nf][r]);
                    }
        }
        __syncthreads();
    }

    float* rt1 = (float*)&sm[0];
    float* rt2 = (float*)&sm[512];
    const int ii = tid >> 2, jc = tid & 3;
    float s[16];
    if (tid < 256) {
#pragma unroll
        for (int jj = 0; jj < 16; ++jj) s[jj] = red[ii * 64 + jc * 16 + jj];
        float mx = s[0];
#pragma unroll
        for (int jj = 1; jj < 16; ++jj) mx = fmaxf(mx, s[jj]);
        rt1[ii * 4 + jc] = mx;
    }
    __syncthreads();
    if (tid < 256) {
        float m4 = fmaxf(fmaxf(rt1[ii * 4], rt1[ii * 4 + 1]),
                         fmaxf(rt1[ii * 4 + 2], rt1[ii * 4 + 3]));
        float sum = 0.f;
#pragma unroll
        for (int jj = 0; jj < 16; ++jj) { s[jj] = __expf(s[jj] - m4); sum += s[jj]; }
        rt2[ii * 4 + jc] = sum;
    }
    __syncthreads();
    if (tid < 256) {
        float tot = rt2[ii * 4] + rt2[ii * 4 + 1] + rt2[ii * 4 + 2] + rt2[ii * 4 + 3];
        float inv = 1.f / tot;
        uint16_t* at = attn + (long)(b * 8 + h) * 4096;
#pragma unroll
        for (int jj = 0; jj < 16; ++jj)
            at[ii * 64 + jc * 16 + jj] = f2bf(s[jj] * inv);
    }
}

// ---------- w2v: Bteff[b][c][k] = sum_h woutT_h[c][i] · (attn_h · Wv_h^T)[i][k] ----------
__global__ __launch_bounds__(512, 1)
void w2v_k(const uint16_t* __restrict__ attn, const uint16_t* __restrict__ woutT,
           const uint16_t* __restrict__ wv_rm, uint16_t* __restrict__ Bteff)
{
    __shared__ uint16_t RT[16384];   // [256 k][64 i], 128B rows, XOR-swizzled
    const int tid  = threadIdx.x;
    const int lane = tid & 63;
    const int wv8  = tid >> 6;
    const int wr   = wv8 >> 2, wc = wv8 & 3;
    const int fr   = lane & 15;
    const int hi4  = lane >> 4;

    const int q8 = gridDim.x >> 3;   // 16
    const int l  = (blockIdx.x & 7) * q8 + (blockIdx.x >> 3);
    const int b  = l >> 2;
    const int mt = (l >> 1) & 1, nt = l & 1;

    f32x4 acc[8][4];
#pragma unroll
    for (int m = 0; m < 8; ++m)
#pragma unroll
        for (int n = 0; n < 4; ++n) acc[m][n] = (f32x4){0.f, 0.f, 0.f, 0.f};

    for (int h = 0; h < 8; ++h) {
        const uint16_t* ah = attn + (long)(b * 8 + h) * 4096;
        f32x4 rac[4][2];
#pragma unroll
        for (int mf = 0; mf < 4; ++mf)
#pragma unroll
            for (int nf = 0; nf < 2; ++nf) rac[mf][nf] = (f32x4){0.f, 0.f, 0.f, 0.f};
#pragma unroll
        for (int ks = 0; ks < 2; ++ks) {
            bf16x8 af[4], bf2[2];
#pragma unroll
            for (int mf = 0; mf < 4; ++mf)
                af[mf] = __builtin_bit_cast(bf16x8,
                    *(const s16x8*)&ah[(mf * 16 + fr) * 64 + ks * 32 + hi4 * 8]);
#pragma unroll
            for (int nf = 0; nf < 2; ++nf) {
                int k = nt * 256 + wv8 * 32 + nf * 16 + fr;
                bf2[nf] = __builtin_bit_cast(bf16x8,
                    *(const s16x8*)&wv_rm[(long)k * 512 + h * 64 + ks * 32 + hi4 * 8]);
            }
#pragma unroll
            for (int mf = 0; mf < 4; ++mf)
#pragma unroll
                for (int nf = 0; nf < 2; ++nf)
                    rac[mf][nf] = __builtin_amdgcn_mfma_f32_16x16x32_bf16(
                        af[mf], bf2[nf], rac[mf][nf], 0, 0, 0);
        }
        __syncthreads();
#pragma unroll
        for (int mf = 0; mf < 4; ++mf)
#pragma unroll
            for (int nf = 0; nf < 2; ++nf)
#pragma unroll
                for (int r = 0; r < 4; ++r) {
                    int i2 = mf * 16 + hi4 * 4 + r;
                    int k  = wv8 * 32 + nf * 16 + fr;
                    RT[k * 64 + (((i2 >> 3) ^ (k & 7)) * 8) + (i2 & 7)] = f2bf(rac[mf][nf][r]);
                }
        __syncthreads();
#pragma unroll
        for (int ks = 0; ks < 2; ++ks) {
            bf16x8 am[8], bm[4];
#pragma unroll
            for (int mf = 0; mf < 8; ++mf) {
                int c = mt * 256 + wr * 128 + mf * 16 + fr;
                am[mf] = __builtin_bit_cast(bf16x8,
                    *(const s16x8*)&woutT[(long)c * 512 + h * 64 + ks * 32 + hi4 * 8]);
            }
#pragma unroll
            for (int nf = 0; nf < 4; ++nf) {
                int k = wc * 64 + nf * 16 + fr;
                bm[nf] = __builtin_bit_cast(bf16x8,
                    *(const s16x8*)&RT[k * 64 + (((ks * 4 + hi4) ^ (k & 7)) * 8)]);
            }
#pragma unroll
            for (int mf = 0; mf < 8; ++mf)
#pragma unroll
                for (int nf = 0; nf < 4; ++nf)
                    acc[mf][nf] = __builtin_amdgcn_mfma_f32_16x16x32_bf16(
                        am[mf], bm[nf], acc[mf][nf], 0, 0, 0);
        }
    }

    uint16_t* o = Bteff + (long)b * 262144;
#pragma unroll
    for (int mf = 0; mf < 8; ++mf)
#pragma unroll
        for (int r = 0; r < 4; ++r) {
            int c = mt * 256 + wr * 128 + mf * 16 + hi4 * 4 + r;
#pragma unroll
            for (int nf = 0; nf < 4; ++nf) {
                int k = nt * 256 + wc * 64 + nf * 16 + fr;
                o[(long)c * 512 + k] = f2bf(acc[mf][nf][r]);
            }
        }
}

// ---------- g128: GEMM2, 128x128 tile m97-structure (32 KiB, 4-resident) + bias ----------
// out[batch*4096+d][co] = sum_c A[d][c] * Bt[batch][co][c] + bias[co], f32 out.
__global__ __launch_bounds__(256, 4)
void g128_k(const uint16_t* __restrict__ A, const uint16_t* __restrict__ Bt,
            float* __restrict__ C, const float* __restrict__ bias,
            int mtiles, int ntiles)
{
    __shared__ uint16_t Al[8192];
    __shared__ uint16_t Bl[8192];
    const int tid  = threadIdx.x;
    const int lane = tid & 63;
    const int wv   = tid >> 6;
    const int wr   = wv >> 1, wc = wv & 1;

    const int q8 = gridDim.x >> 3;
    const int l  = (blockIdx.x & 7) * q8 + (blockIdx.x >> 3);
    const int per   = mtiles * ntiles;
    const int batch = l / per;
    const int rem   = l - batch * per;
    const int mt    = rem / ntiles, nt = rem - mt * ntiles;

    const uint16_t* arow = A + ((long)batch * 4096 + mt * 128) * 512;
    const uint16_t* brow = Bt + (long)batch * 262144 + (long)nt * 128 * 512;

    f32x4 acc[4][4];
#pragma unroll
    for (int m = 0; m < 4; ++m)
#pragma unroll
        for (int n = 0; n < 4; ++n) acc[m][n] = (f32x4){0.f, 0.f, 0.f, 0.f};

    for (int k0 = 0; k0 < 512; k0 += 64) {
#pragma unroll
        for (int s2 = 0; s2 < 4; ++s2) {
            int cb  = s2 * 256 + wv * 64;
            int ci  = cb + lane;
            int row = ci >> 3;
            int cs  = (ci & 7) ^ (row & 7);
            async16(&Al[cb * 8], arow + (long)row * 512 + k0 + cs * 8);
            async16(&Bl[cb * 8], brow + (long)row * 512 + k0 + cs * 8);
        }
        __syncthreads();
#pragma unroll
        for (int ks = 0; ks < 2; ++ks) {
            bf16x8 af[4], bfr[4];
#pragma unroll
            for (int m = 0; m < 4; ++m) {
                int row = wr * 64 + m * 16 + (lane & 15);
                int ch  = ks * 4 + (lane >> 4);
                af[m] = __builtin_bit_cast(bf16x8,
                    *(const s16x8*)&Al[row * 64 + ((ch ^ (row & 7)) * 8)]);
            }
#pragma unroll
            for (int n = 0; n < 4; ++n) {
                int row = wc * 64 + n * 16 + (lane & 15);
                int ch  = ks * 4 + (lane >> 4);
                bfr[n] = __builtin_bit_cast(bf16x8,
                    *(const s16x8*)&Bl[row * 64 + ((ch ^ (row & 7)) * 8)]);
            }
#pragma unroll
            for (int m = 0; m < 4; ++m)
#pragma unroll
                for (int n = 0; n < 4; ++n)
                    acc[m][n] = __builtin_amdgcn_mfma_f32_16x16x32_bf16(
                        af[m], bfr[n], acc[m][n], 0, 0, 0);
        }
        __syncthreads();
    }

    const long crow0 = (long)batch * 4096 + mt * 128 + wr * 64;
    const int  col0  = nt * 128 + wc * 64;
    float bv[4];
#pragma unroll
    for (int n = 0; n < 4; ++n)
        bv[n] = bias[col0 + n * 16 + (lane & 15)];
#pragma unroll
    for (int m = 0; m < 4; ++m)
#pragma unroll
        for (int r = 0; r < 4; ++r) {
            long row = crow0 + m * 16 + (lane >> 4) * 4 + r;
#pragma unroll
            for (int n = 0; n < 4; ++n)
                C[row * 512 + col0 + n * 16 + (lane & 15)] = acc[m][n][r] + bv[n];
        }
}

// ---------- launcher ----------
extern "C" void kernel_launch(void* const* d_in, const int* in_sizes, int n_in,
                              void* d_out, int out_size, void* d_ws, size_t ws_size,
                              hipStream_t stream)
{
    const float* x     = (const float*)d_in[0];
    const float* w_qkv = (const float*)d_in[1];
    const float* w_out = (const float*)d_in[2];
    const float* b_out = (const float*)d_in[3];
    float* out = (float*)d_out;

    char* ws = (char*)d_ws;
    uint16_t* xb    = (uint16_t*)(ws);                     // 134,217,728
    uint16_t* xT    = (uint16_t*)(ws + 134217728L);        // 134,217,728
    uint16_t* G     = (uint16_t*)(ws + 268435456L);        // 16,777,216  [32][512][512]
    uint16_t* attn  = (uint16_t*)(ws + 285212672L);        // 2,097,152
    uint16_t* Bteff = (uint16_t*)(ws + 287309824L);        // 16,777,216
    uint16_t* wqTs  = (uint16_t*)(ws + 304087040L);        // 524,288
    uint16_t* wkT   = (uint16_t*)(ws + 304611328L);        // 524,288
    uint16_t* woutT = (uint16_t*)(ws + 305135616L);        // 524,288
    uint16_t* wv_rm = (uint16_t*)(ws + 305659904L);        // 524,288
    // total 306,184,192 B

    // x -> xb + xT, plus weight prep (merged)
    xtw_k<<<20480, 256, 0, stream>>>(x, w_qkv, w_out, xb, xT,
                                     wqTs, wkT, woutT, wv_rm);

    // Gram (unsplit K=4096): diag + upper triangle, mirrored
    g128G_k<<<320, 256, 0, stream>>>(xT, G);

    // fused sim + softmax -> attn
    simfull_k<<<256, 512, 0, stream>>>(G, wkT, wqTs, attn);

    // fused w2 + weff -> Bteff
    w2v_k<<<128, 512, 0, stream>>>(attn, woutT, wv_rm, Bteff);

    // out[b] = xb[b] @ Bteff[b]^T + b_out  (128^2 multi-resident)
    g128_k<<<4096, 256, 0, stream>>>(xb, Bteff, out, b_out, 32, 4);
}

// Round 12
// 378.131 us; speedup vs baseline: 1.0630x; 1.0630x over previous
//
#include <hip/hip_runtime.h>
#include <hip/hip_bf16.h>
#include <stdint.h>

// ---------- types ----------
using bf16x8 = __attribute__((ext_vector_type(8))) __bf16;
using s16x8  = __attribute__((ext_vector_type(8))) short;
using f32x4  = __attribute__((ext_vector_type(4))) float;

__device__ __forceinline__ uint16_t f2bf(float f) {
    uint32_t u = __builtin_bit_cast(uint32_t, f);
    u += 0x7fffu + ((u >> 16) & 1u);   // RNE
    return (uint16_t)(u >> 16);
}
__device__ __forceinline__ float bf2f(uint16_t h) {
    return __builtin_bit_cast(float, (uint32_t)h << 16);
}

__device__ __forceinline__ void async16(uint16_t* lds_dst, const uint16_t* g_src) {
    __builtin_amdgcn_global_load_lds(
        (const __attribute__((address_space(1))) void*)g_src,
        (__attribute__((address_space(3))) void*)lds_dst,
        16, 0, 0);
}

// ---------- merged weight prep (4 sections x 1024 blocks) ----------
__global__ void wprep_all(const float* __restrict__ wqkv, const float* __restrict__ wout,
                          uint16_t* __restrict__ wqTs, uint16_t* __restrict__ wkTcat,
                          uint16_t* __restrict__ woutT, uint16_t* __restrict__ wv_rm)
{
    int sec = blockIdx.x >> 10;
    int idx = (blockIdx.x & 1023) * 256 + threadIdx.x;   // over 512*512
    int co = idx >> 9, r = idx & 511;
    if (sec == 0) {
        wqTs[co * 512 + r] = f2bf(wqkv[r * 1536 + co] * 0.125f);
    } else if (sec == 1) {
        uint16_t v = f2bf(wqkv[r * 1536 + 512 + co]);
        wkTcat[co * 1024 + r] = v;
        wkTcat[co * 1024 + 512 + r] = v;
    } else if (sec == 2) {
        woutT[co * 512 + r] = f2bf(wout[r * 512 + co]);
    } else {
        wv_rm[co * 512 + r] = f2bf(wqkv[co * 1536 + 1024 + r]);
    }
}

// ---------- xt_k: x f32 -> xb (row-major bf16) + xT (transposed bf16 [b][512][4096]) ----------
__global__ __launch_bounds__(256, 4)
void xt_k(const float* __restrict__ x, uint16_t* __restrict__ xb, uint16_t* __restrict__ xT)
{
    __shared__ uint16_t lt[64 * 68];
    const int tid = threadIdx.x;
    const int bi = blockIdx.x;
    const int b = bi >> 9;
    const int rem = bi & 511;
    const int st = rem >> 3, ct = rem & 7;     // 64-spatial x 64-chan tile
    const int c4 = (tid & 15) * 4;
#pragma unroll
    for (int rep = 0; rep < 4; ++rep) {
        int r = (tid >> 4) + rep * 16;
        long gs = (long)(b * 4096 + st * 64 + r) * 512 + ct * 64 + c4;
        float4 v = *(const float4*)(x + gs);
        uint16_t t[4];
        t[0] = f2bf(v.x); t[1] = f2bf(v.y); t[2] = f2bf(v.z); t[3] = f2bf(v.w);
        *(ushort4*)(xb + gs) = *(const ushort4*)t;
#pragma unroll
        for (int q = 0; q < 4; ++q) lt[r * 68 + c4 + q] = t[q];
    }
    __syncthreads();
    const int s4 = (tid & 15) * 4;
#pragma unroll
    for (int rep = 0; rep < 4; ++rep) {
        int c = (tid >> 4) + rep * 16;
        uint16_t t[4];
#pragma unroll
        for (int q = 0; q < 4; ++q) t[q] = lt[(s4 + q) * 68 + c];
        *(ushort4*)(xT + (long)(b * 512 + ct * 64 + c) * 4096 + st * 64 + s4) =
            *(const ushort4*)t;
    }
}

// ---------- g8: 256x256 tile, BK=64, 8-phase counted-vmcnt (verified R5/R7) ----------
template<bool OUTF32>
__global__ __launch_bounds__(512, 2)
void g8_k(const uint16_t* __restrict__ A, const uint16_t* __restrict__ Bt,
          void* __restrict__ Cp, const float* __restrict__ bias,
          int K, int lda, int ldb, int ldc, int mtiles, int ntiles,
          long abr, long bbe, long cbr)
{
    __shared__ uint16_t lds[65536];
    const int tid  = threadIdx.x;
    const int lane = tid & 63;
    const int wv   = tid >> 6;
    const int wr   = wv >> 2, wc = wv & 3;

    const int q8 = gridDim.x >> 3;
    const int l  = (blockIdx.x & 7) * q8 + (blockIdx.x >> 3);
    const int per   = mtiles * ntiles;
    const int batch = l / per;
    const int rem   = l - batch * per;
    const int mt    = rem / ntiles, nt = rem - mt * ntiles;

    const long arow0 = abr * batch + (long)mt * 256;
    const uint16_t* abase = A + arow0 * (long)lda;
    const uint16_t* btb   = Bt + bbe * batch + (long)nt * 256 * ldb;

    const int fr = lane & 15;
    const int cx0 = (((0 << 2) | (lane >> 4)) ^ (fr & 7)) * 8;
    const int cx1 = (((1 << 2) | (lane >> 4)) ^ (fr & 7)) * 8;
    const int baseA = wr * 8192 + fr * 64;
    const int baseB = (2 + (wc >> 1)) * 8192 + ((wc & 1) * 64 + fr) * 64;

    const int NT = K >> 6;

    auto stage = [&](int slot, const uint16_t* gb, int rstride, int k0) {
#pragma unroll
        for (int i = 0; i < 2; ++i) {
            int si = i * 512 + wv * 64 + lane;
            int rr = si >> 3, cc = (si & 7) ^ (rr & 7);
            async16(&lds[slot * 8192 + (i * 512 + wv * 64) * 8],
                    gb + (long)rr * rstride + k0 + cc * 8);
        }
    };

    f32x4 acc[8][4];
#pragma unroll
    for (int m = 0; m < 8; ++m)
#pragma unroll
        for (int n = 0; n < 4; ++n) acc[m][n] = (f32x4){0.f, 0.f, 0.f, 0.f};

    bf16x8 af[4], bfq[4];

    auto rdA = [&](int mb, int b4, int cx) {
#pragma unroll
        for (int mi = 0; mi < 4; ++mi)
            af[mi] = __builtin_bit_cast(bf16x8,
                *(const s16x8*)&lds[b4 * 8192 + baseA + (mb + mi) * 1024 + cx]);
    };
    auto rdB = [&](int b4, int cx) {
#pragma unroll
        for (int n = 0; n < 4; ++n)
            bfq[n] = __builtin_bit_cast(bf16x8,
                *(const s16x8*)&lds[b4 * 8192 + baseB + n * 1024 + cx]);
    };
    auto mm = [&](int mb) {
        asm volatile("s_waitcnt lgkmcnt(0)" ::: "memory");
        __builtin_amdgcn_sched_barrier(0);
        __builtin_amdgcn_s_setprio(1);
#pragma unroll
        for (int mi = 0; mi < 4; ++mi)
#pragma unroll
            for (int n = 0; n < 4; ++n)
                acc[mb + mi][n] = __builtin_amdgcn_mfma_f32_16x16x32_bf16(
                    af[mi], bfq[n], acc[mb + mi][n], 0, 0, 0);
        __builtin_amdgcn_s_setprio(0);
        __builtin_amdgcn_s_barrier();
    };

    stage(0, abase,              lda, 0);
    stage(1, abase + 128L * lda, lda, 0);
    stage(2, btb,                ldb, 0);
    stage(3, btb + 128L * ldb,   ldb, 0);
    stage(6, btb,                ldb, 64);
    stage(7, btb + 128L * ldb,   ldb, 64);
    asm volatile("s_waitcnt vmcnt(4)" ::: "memory");
    __builtin_amdgcn_sched_barrier(0);
    __builtin_amdgcn_s_barrier();

    for (int it = 0; it < (NT >> 1); ++it) {
        const int E = 2 * it, Od = E + 1;
        const bool s3 = (E + 2) < NT;
        const bool s7 = (Od + 2) < NT;
        const int kE2 = (E + 2) << 6, kO1 = Od << 6, kO2 = (Od + 2) << 6;

        rdB(0, cx0); rdA(0, 0, cx0);
        stage(4, abase,              lda, kO1);
        stage(5, abase + 128L * lda, lda, kO1);
        __builtin_amdgcn_s_barrier();
        mm(0);
        rdA(4, 0, cx0);
        __builtin_amdgcn_s_barrier();
        mm(4);
        rdB(0, cx1); rdA(0, 0, cx1);
        __builtin_amdgcn_s_barrier();
        mm(0);
        rdA(4, 0, cx1);
        if (s3) {
            stage(2, btb,              ldb, kE2);
            stage(3, btb + 128L * ldb, ldb, kE2);
            asm volatile("s_waitcnt vmcnt(4)" ::: "memory");
        } else {
            asm volatile("s_waitcnt vmcnt(0)" ::: "memory");
        }
        __builtin_amdgcn_sched_barrier(0);
        __builtin_amdgcn_s_barrier();
        mm(4);
        rdB(4, cx0); rdA(0, 4, cx0);
        if (s3) {
            stage(0, abase,              lda, kE2);
            stage(1, abase + 128L * lda, lda, kE2);
        }
        __builtin_amdgcn_s_barrier();
        mm(0);
        rdA(4, 4, cx0);
        __builtin_amdgcn_s_barrier();
        mm(4);
        rdB(4, cx1); rdA(0, 4, cx1);
        __builtin_amdgcn_s_barrier();
        mm(0);
        rdA(4, 4, cx1);
        if (s7) {
            stage(6, btb,              ldb, kO2);
            stage(7, btb + 128L * ldb, ldb, kO2);
            asm volatile("s_waitcnt vmcnt(4)" ::: "memory");
        } else {
            asm volatile("s_waitcnt vmcnt(0)" ::: "memory");
        }
        __builtin_amdgcn_sched_barrier(0);
        __builtin_amdgcn_s_barrier();
        mm(4);
    }

    const long crow0 = cbr * batch + (long)mt * 256 + wr * 128;
    const int  col0  = nt * 256 + wc * 64;
    float bv[4];
#pragma unroll
    for (int n = 0; n < 4; ++n)
        bv[n] = bias ? bias[col0 + n * 16 + (lane & 15)] : 0.f;
#pragma unroll
    for (int m = 0; m < 8; ++m) {
#pragma unroll
        for (int r = 0; r < 4; ++r) {
            long row = crow0 + m * 16 + (lane >> 4) * 4 + r;
#pragma unroll
            for (int n = 0; n < 4; ++n) {
                int col = col0 + n * 16 + (lane & 15);
                float v = acc[m][n][r];
                if constexpr (OUTF32)
                    ((float*)Cp)[row * (long)ldc + col] = v + bv[n];
                else
                    ((uint16_t*)Cp)[row * (long)ldc + col] = f2bf(v);
            }
        }
    }
}

// ---------- g8G: Gram with symmetry — 3 quadrants per (b,z), mirror off-diag ----------
// Gcat[b][c][z*512+c'] = sum_k xT[b][c][zK+k]*xT[b][c'][zK+k]; symmetric per z.
__global__ __launch_bounds__(512, 2)
void g8G_k(const uint16_t* __restrict__ X, uint16_t* __restrict__ Gcat)
{
    __shared__ uint16_t lds[65536];
    const int tid  = threadIdx.x;
    const int lane = tid & 63;
    const int wv   = tid >> 6;
    const int wr   = wv >> 2, wc = wv & 3;

    // XCD swizzle (grid=192, %8==0): q8=24, consecutive l share (b,z)
    const int q8 = gridDim.x >> 3;
    const int l  = (blockIdx.x & 7) * q8 + (blockIdx.x >> 3);
    const int g  = l / 3;
    const int quad = l - g * 3;                  // 0:(0,0) 1:(1,1) 2:(0,1)
    const int b = g >> 1, z = g & 1;
    const int mt = (quad == 1) ? 1 : 0;
    const int nt = (quad == 0) ? 0 : 1;

    const uint16_t* xb0 = X + (long)b * 512 * 4096 + z * 2048;
    const uint16_t* abase = xb0 + (long)mt * 256 * 4096;
    const uint16_t* btb   = xb0 + (long)nt * 256 * 4096;

    const int fr = lane & 15;
    const int cx0 = (((0 << 2) | (lane >> 4)) ^ (fr & 7)) * 8;
    const int cx1 = (((1 << 2) | (lane >> 4)) ^ (fr & 7)) * 8;
    const int baseA = wr * 8192 + fr * 64;
    const int baseB = (2 + (wc >> 1)) * 8192 + ((wc & 1) * 64 + fr) * 64;

    const int NT = 32;   // K=2048

    auto stage = [&](int slot, const uint16_t* gb, int k0) {
#pragma unroll
        for (int i = 0; i < 2; ++i) {
            int si = i * 512 + wv * 64 + lane;
            int rr = si >> 3, cc = (si & 7) ^ (rr & 7);
            async16(&lds[slot * 8192 + (i * 512 + wv * 64) * 8],
                    gb + (long)rr * 4096 + k0 + cc * 8);
        }
    };

    f32x4 acc[8][4];
#pragma unroll
    for (int m = 0; m < 8; ++m)
#pragma unroll
        for (int n = 0; n < 4; ++n) acc[m][n] = (f32x4){0.f, 0.f, 0.f, 0.f};

    bf16x8 af[4], bfq[4];
    auto rdA = [&](int mb, int b4, int cx) {
#pragma unroll
        for (int mi = 0; mi < 4; ++mi)
            af[mi] = __builtin_bit_cast(bf16x8,
                *(const s16x8*)&lds[b4 * 8192 + baseA + (mb + mi) * 1024 + cx]);
    };
    auto rdB = [&](int b4, int cx) {
#pragma unroll
        for (int n = 0; n < 4; ++n)
            bfq[n] = __builtin_bit_cast(bf16x8,
                *(const s16x8*)&lds[b4 * 8192 + baseB + n * 1024 + cx]);
    };
    auto mm = [&](int mb) {
        asm volatile("s_waitcnt lgkmcnt(0)" ::: "memory");
        __builtin_amdgcn_sched_barrier(0);
        __builtin_amdgcn_s_setprio(1);
#pragma unroll
        for (int mi = 0; mi < 4; ++mi)
#pragma unroll
            for (int n = 0; n < 4; ++n)
                acc[mb + mi][n] = __builtin_amdgcn_mfma_f32_16x16x32_bf16(
                    af[mi], bfq[n], acc[mb + mi][n], 0, 0, 0);
        __builtin_amdgcn_s_setprio(0);
        __builtin_amdgcn_s_barrier();
    };

    stage(0, abase,               0);
    stage(1, abase + 128L * 4096, 0);
    stage(2, btb,                 0);
    stage(3, btb + 128L * 4096,   0);
    stage(6, btb,                 64);
    stage(7, btb + 128L * 4096,   64);
    asm volatile("s_waitcnt vmcnt(4)" ::: "memory");
    __builtin_amdgcn_sched_barrier(0);
    __builtin_amdgcn_s_barrier();

    for (int it = 0; it < (NT >> 1); ++it) {
        const int E = 2 * it, Od = E + 1;
        const bool s3 = (E + 2) < NT;
        const bool s7 = (Od + 2) < NT;
        const int kE2 = (E + 2) << 6, kO1 = Od << 6, kO2 = (Od + 2) << 6;

        rdB(0, cx0); rdA(0, 0, cx0);
        stage(4, abase,               kO1);
        stage(5, abase + 128L * 4096, kO1);
        __builtin_amdgcn_s_barrier();
        mm(0);
        rdA(4, 0, cx0);
        __builtin_amdgcn_s_barrier();
        mm(4);
        rdB(0, cx1); rdA(0, 0, cx1);
        __builtin_amdgcn_s_barrier();
        mm(0);
        rdA(4, 0, cx1);
        if (s3) {
            stage(2, btb,               kE2);
            stage(3, btb + 128L * 4096, kE2);
            asm volatile("s_waitcnt vmcnt(4)" ::: "memory");
        } else {
            asm volatile("s_waitcnt vmcnt(0)" ::: "memory");
        }
        __builtin_amdgcn_sched_barrier(0);
        __builtin_amdgcn_s_barrier();
        mm(4);
        rdB(4, cx0); rdA(0, 4, cx0);
        if (s3) {
            stage(0, abase,               kE2);
            stage(1, abase + 128L * 4096, kE2);
        }
        __builtin_amdgcn_s_barrier();
        mm(0);
        rdA(4, 4, cx0);
        __builtin_amdgcn_s_barrier();
        mm(4);
        rdB(4, cx1); rdA(0, 4, cx1);
        __builtin_amdgcn_s_barrier();
        mm(0);
        rdA(4, 4, cx1);
        if (s7) {
            stage(6, btb,               kO2);
            stage(7, btb + 128L * 4096, kO2);
            asm volatile("s_waitcnt vmcnt(4)" ::: "memory");
        } else {
            asm volatile("s_waitcnt vmcnt(0)" ::: "memory");
        }
        __builtin_amdgcn_sched_barrier(0);
        __builtin_amdgcn_s_barrier();
        mm(4);
    }

    uint16_t* o = Gcat + (long)b * 524288;
    const int zoff = z * 512;
    const int row0 = mt * 256 + wr * 128;
    const int col0 = nt * 256 + wc * 64;
#pragma unroll
    for (int m = 0; m < 8; ++m) {
#pragma unroll
        for (int r = 0; r < 4; ++r) {
            int row = row0 + m * 16 + (lane >> 4) * 4 + r;
#pragma unroll
            for (int n = 0; n < 4; ++n)
                o[(long)row * 1024 + zoff + col0 + n * 16 + (lane & 15)] = f2bf(acc[m][n][r]);
        }
        if (quad == 2) {
            // mirror: element (row, col) -> (col, row); r-index contiguous -> ushort4
            int rbase = row0 + m * 16 + (lane >> 4) * 4;
#pragma unroll
            for (int n = 0; n < 4; ++n) {
                int col = col0 + n * 16 + (lane & 15);
                uint16_t t[4];
#pragma unroll
                for (int r = 0; r < 4; ++r) t[r] = f2bf(acc[m][n][r]);
                *(ushort4*)&o[(long)col * 1024 + zoff + rbase] = *(const ushort4*)t;
            }
        }
    }
}

// ---------- simfull: per (b,h): T1t = WkT·G (K=1024 cat) -> sim = WqTs·T1t -> softmax ----------
// T1t stored hi/lo split-bf16 (two LDS planes) so stage2 sees ~f32 precision.
__global__ __launch_bounds__(512, 1)
void simfull_k(const uint16_t* __restrict__ Gcat, const uint16_t* __restrict__ wkTcat,
               const uint16_t* __restrict__ wqTs, uint16_t* __restrict__ attnT)
{
    __shared__ uint16_t sm[73728];   // 147,456 B
    const int tid  = threadIdx.x;
    const int lane = tid & 63;
    const int wv   = tid >> 6;
    const int fr   = lane & 15;
    const int bi = blockIdx.x;
    const int h = bi >> 5;
    const int b = (bi & 7) * 4 + ((bi >> 3) & 3);   // same-b blocks share an XCD

    const uint16_t* gb  = Gcat + (long)b * 524288;
    const uint16_t* ab  = wkTcat + (long)h * 64 * 1024;
    const uint16_t* qb2 = wqTs + (long)h * 64 * 512;

    f32x4 acc[4][4];
#pragma unroll
    for (int mf = 0; mf < 4; ++mf)
#pragma unroll
        for (int nf = 0; nf < 4; ++nf) acc[mf][nf] = (f32x4){0.f, 0.f, 0.f, 0.f};

    for (int t = 0; t < 16; ++t) {
        const int k0 = t * 64;
#pragma unroll
        for (int i = 0; i < 8; ++i) {
            int si = i * 64 + lane;
            int rr = si >> 3, cc = (si & 7) ^ (rr & 7);
            async16(&sm[wv * 4096 + i * 512],
                    gb + (long)(wv * 64 + rr) * 1024 + k0 + cc * 8);
        }
        {
            int rr = wv * 8 + (lane >> 3);
            int cc = (lane & 7) ^ (rr & 7);
            async16(&sm[32768 + wv * 512],
                    ab + (long)rr * 1024 + k0 + cc * 8);
        }
        asm volatile("s_waitcnt vmcnt(0)" ::: "memory");
        __syncthreads();
#pragma unroll
        for (int ks = 0; ks < 2; ++ks) {
            bf16x8 af[4], bfq[4];
            int cx = ((ks * 4 + (lane >> 4)) ^ (fr & 7)) * 8;
#pragma unroll
            for (int mf = 0; mf < 4; ++mf)
                af[mf] = __builtin_bit_cast(bf16x8,
                    *(const s16x8*)&sm[32768 + (mf * 16 + fr) * 64 + cx]);
#pragma unroll
            for (int nf = 0; nf < 4; ++nf)
                bfq[nf] = __builtin_bit_cast(bf16x8,
                    *(const s16x8*)&sm[(wv * 64 + nf * 16 + fr) * 64 + cx]);
#pragma unroll
            for (int mf = 0; mf < 4; ++mf)
#pragma unroll
                for (int nf = 0; nf < 4; ++nf)
                    acc[mf][nf] = __builtin_amdgcn_mfma_f32_16x16x32_bf16(
                        af[mf], bfq[nf], acc[mf][nf], 0, 0, 0);
        }
        __syncthreads();
    }

#pragma unroll
    for (int mf = 0; mf < 4; ++mf)
#pragma unroll
        for (int nf = 0; nf < 4; ++nf)
#pragma unroll
            for (int r = 0; r < 4; ++r) {
                int j = mf * 16 + (lane >> 4) * 4 + r;
                int c = wv * 64 + nf * 16 + fr;
                float v = acc[mf][nf][r];
                uint16_t hi = f2bf(v);
                int off = j * 512 + ((c >> 3) ^ (j & 7)) * 8 + (c & 7);
                sm[off] = hi;
                sm[32768 + off] = f2bf(v - bf2f(hi));
            }
    __syncthreads();

    f32x4 a2[4][4];
#pragma unroll
    for (int mf = 0; mf < 4; ++mf)
#pragma unroll
        for (int nf = 0; nf < 4; ++nf) a2[mf][nf] = (f32x4){0.f, 0.f, 0.f, 0.f};
#pragma unroll
    for (int ks = 0; ks < 2; ++ks) {
        bf16x8 af[4], bh[4], bl[4];
#pragma unroll
        for (int mf = 0; mf < 4; ++mf)
            af[mf] = __builtin_bit_cast(bf16x8,
                *(const s16x8*)&qb2[(long)(mf * 16 + fr) * 512 + wv * 64 + ks * 32 + (lane >> 4) * 8]);
#pragma unroll
        for (int nf = 0; nf < 4; ++nf) {
            int j = nf * 16 + fr;
            int ch = (wv * 8 + ks * 4 + (lane >> 4)) ^ (fr & 7);
            bh[nf] = __builtin_bit_cast(bf16x8, *(const s16x8*)&sm[j * 512 + ch * 8]);
            bl[nf] = __builtin_bit_cast(bf16x8, *(const s16x8*)&sm[32768 + j * 512 + ch * 8]);
        }
#pragma unroll
        for (int mf = 0; mf < 4; ++mf)
#pragma unroll
            for (int nf = 0; nf < 4; ++nf) {
                a2[mf][nf] = __builtin_amdgcn_mfma_f32_16x16x32_bf16(
                    af[mf], bh[nf], a2[mf][nf], 0, 0, 0);
                a2[mf][nf] = __builtin_amdgcn_mfma_f32_16x16x32_bf16(
                    af[mf], bl[nf], a2[mf][nf], 0, 0, 0);
            }
    }

    float* red = (float*)&sm[65536];
    for (int w = 0; w < 8; ++w) {
        if (wv == w) {
#pragma unroll
            for (int mf = 0; mf < 4; ++mf)
#pragma unroll
                for (int nf = 0; nf < 4; ++nf)
#pragma unroll
                    for (int r = 0; r < 4; ++r) {
                        int i = mf * 16 + (lane >> 4) * 4 + r;
                        int j = nf * 16 + fr;
                        float* p = &red[i * 64 + j];
                        *p = (w == 0) ? a2[mf][nf][r] : (*p + a2[mf][nf][r]);
                    }
        }
        __syncthreads();
    }

    float* rt1 = (float*)&sm[0];
    float* rt2 = (float*)&sm[512];
    const int i = tid >> 2, jc = tid & 3;
    float s[16];
    if (tid < 256) {
#pragma unroll
        for (int jj = 0; jj < 16; ++jj) s[jj] = red[i * 64 + jc * 16 + jj];
        float mx = s[0];
#pragma unroll
        for (int jj = 1; jj < 16; ++jj) mx = fmaxf(mx, s[jj]);
        rt1[i * 4 + jc] = mx;
    }
    __syncthreads();
    if (tid < 256) {
        float m4 = fmaxf(fmaxf(rt1[i * 4], rt1[i * 4 + 1]),
                         fmaxf(rt1[i * 4 + 2], rt1[i * 4 + 3]));
        float sum = 0.f;
#pragma unroll
        for (int jj = 0; jj < 16; ++jj) { s[jj] = __expf(s[jj] - m4); sum += s[jj]; }
        rt2[i * 4 + jc] = sum;
    }
    __syncthreads();
    if (tid < 256) {
        float tot = rt2[i * 4] + rt2[i * 4 + 1] + rt2[i * 4 + 2] + rt2[i * 4 + 3];
        float inv = 1.f / tot;
        uint16_t* at = attnT + (long)(b * 8 + h) * 4096;
#pragma unroll
        for (int jj = 0; jj < 16; ++jj)
            at[(jc * 16 + jj) * 64 + i] = f2bf(s[jj] * inv);
    }
}

// ---------- w2: W2T[b][c][h*64+j] = sum_i attn[i][j]*w_out[h*64+i][c] ----------
__global__ __launch_bounds__(256, 1)
void w2_k(const uint16_t* __restrict__ attnT, const uint16_t* __restrict__ woutT,
          uint16_t* __restrict__ W2T)
{
    const int tid = threadIdx.x;
    const int lane = tid & 63, wv = tid >> 6;
    const int b = blockIdx.x >> 3, h = blockIdx.x & 7;
    const uint16_t* at = attnT + (long)blockIdx.x * 4096;

    bf16x8 bfrag[2][4];
#pragma unroll
    for (int ks = 0; ks < 2; ++ks)
#pragma unroll
        for (int nf = 0; nf < 4; ++nf) {
            s16x8 v = *(const s16x8*)&at[(nf * 16 + (lane & 15)) * 64 + ks * 32 + (lane >> 4) * 8];
            bfrag[ks][nf] = __builtin_bit_cast(bf16x8, v);
        }
    f32x4 acc[8][4];
#pragma unroll
    for (int mf = 0; mf < 8; ++mf)
#pragma unroll
        for (int nf = 0; nf < 4; ++nf) acc[mf][nf] = (f32x4){0.f, 0.f, 0.f, 0.f};
#pragma unroll
    for (int mf = 0; mf < 8; ++mf) {
        int c = wv * 128 + mf * 16 + (lane & 15);
#pragma unroll
        for (int ks = 0; ks < 2; ++ks) {
            s16x8 v = *(const s16x8*)&woutT[(long)c * 512 + h * 64 + ks * 32 + (lane >> 4) * 8];
            bf16x8 af = __builtin_bit_cast(bf16x8, v);
#pragma unroll
            for (int nf = 0; nf < 4; ++nf)
                acc[mf][nf] = __builtin_amdgcn_mfma_f32_16x16x32_bf16(
                    af, bfrag[ks][nf], acc[mf][nf], 0, 0, 0);
        }
    }
    uint16_t* o = W2T + (long)b * 512 * 512;
#pragma unroll
    for (int mf = 0; mf < 8; ++mf)
#pragma unroll
        for (int nf = 0; nf < 4; ++nf)
#pragma unroll
            for (int r = 0; r < 4; ++r) {
                int c = wv * 128 + mf * 16 + (lane >> 4) * 4 + r;
                int j = nf * 16 + (lane & 15);
                o[(long)c * 512 + h * 64 + j] = f2bf(acc[mf][nf][r]);
            }
}

// ---------- launcher ----------
extern "C" void kernel_launch(void* const* d_in, const int* in_sizes, int n_in,
                              void* d_out, int out_size, void* d_ws, size_t ws_size,
                              hipStream_t stream)
{
    const float* x     = (const float*)d_in[0];
    const float* w_qkv = (const float*)d_in[1];
    const float* w_out = (const float*)d_in[2];
    const float* b_out = (const float*)d_in[3];
    float* out = (float*)d_out;

    char* ws = (char*)d_ws;
    uint16_t* xb     = (uint16_t*)(ws);                     // 134,217,728
    uint16_t* xT     = (uint16_t*)(ws + 134217728L);        // 134,217,728
    uint16_t* Gcat   = (uint16_t*)(ws + 268435456L);        // 33,554,432
    uint16_t* attnT  = (uint16_t*)(ws + 301989888L);        // 2,097,152
    uint16_t* W2T    = (uint16_t*)(ws + 304087040L);        // 16,777,216
    uint16_t* Bteff  = (uint16_t*)(ws + 320864256L);        // 33,554,432
    uint16_t* wqTs   = (uint16_t*)(ws + 354418688L);        // 524,288
    uint16_t* wkTcat = (uint16_t*)(ws + 354942976L);        // 1,048,576
    uint16_t* woutT  = (uint16_t*)(ws + 355991552L);        // 524,288
    uint16_t* wv_rm  = (uint16_t*)(ws + 356515840L);        // 524,288

    wprep_all<<<4096, 256, 0, stream>>>(w_qkv, w_out, wqTs, wkTcat, woutT, wv_rm);

    // x -> xb (row-major bf16) + xT (channel-major bf16)
    xt_k<<<16384, 256, 0, stream>>>(x, xb, xT);

    // Gram with symmetry: 3 quadrants per (b,z), mirrored epilogue
    g8G_k<<<192, 512, 0, stream>>>(xT, Gcat);

    // fused sim + softmax -> attnT
    simfull_k<<<256, 512, 0, stream>>>(Gcat, wkTcat, wqTs, attnT);

    // per-batch attention-projected weights
    w2_k<<<256, 256, 0, stream>>>(attnT, woutT, W2T);

    // Bteff[b][c][k] = sum_{c'} W2T[b][c][c'] * Wv[k][c']
    g8_k<false><<<128, 512, 0, stream>>>(
        W2T, wv_rm, Bteff, nullptr,
        512, 512, 512, 512, 2, 2, 512L, 0L, 512L);

    // GEMM2: out[b] = xb[b] @ Bteff[b]^T + b_out
    g8_k<true><<<1024, 512, 0, stream>>>(
        xb, Bteff, out, b_out,
        512, 512, 512, 512, 16, 2, 4096L, 262144L, 4096L);
}